// Round 16
// baseline (933.160 us; speedup 1.0000x reference)
//
#include <hip/hip_runtime.h>

#define N_NODES 50000
#define N_EDGES 1600000
#define FX 128
#define FE 8
#define FIN 136          // FX + FE
#define NPAD 50048       // pad rows so 64-row tiles can over-read safely
#define NB_SCAN 196      // ceil(N_NODES / 256)
#define NXCD 8
#define NPC 6250         // nodes per dst class (fill partitioning)
#define FCHUNK 2048      // edges per chunk in fill
#define NCHUNK ((N_EDGES + FCHUNK - 1) / FCHUNK)   // 782
#define KP 168           // LDS A stride (elems)
#define KP2 136          // LDS h3 stride for fused fc (elems), aliased into As

typedef short short8v __attribute__((ext_vector_type(8)));
typedef float float4v __attribute__((ext_vector_type(4)));

__device__ inline float bf2f(unsigned short h) {
    return __uint_as_float((unsigned)h << 16);
}
__device__ inline unsigned short f2bf(float f) {   // round-to-nearest-even
    unsigned u = __float_as_uint(f);
    u = (u + 0x7FFF + ((u >> 16) & 1)) >> 16;
    return (unsigned short)u;
}

// ---------------------------------------------------------------- CSR build (y = branch)
__global__ void hist_kernel(const int* __restrict__ ei0, const int* __restrict__ ei1,
                            int* __restrict__ deg0, int* __restrict__ deg1) {
    const int* ei = blockIdx.y ? ei1 : ei0;
    int* deg      = blockIdx.y ? deg1 : deg0;
    int e = blockIdx.x * 256 + threadIdx.x;
    if (e >= N_EDGES) return;
    atomicAdd(&deg[ei[N_EDGES + e]], 1);             // plain load: leave dst L3-resident
}

__global__ void scan1_kernel(const int* __restrict__ deg0, const int* __restrict__ deg1,
                             int* __restrict__ p0, int* __restrict__ p1) {
    const int* deg = blockIdx.y ? deg1 : deg0;
    int* partial   = blockIdx.y ? p1 : p0;
    __shared__ int red[256];
    int i = blockIdx.x * 256 + threadIdx.x;
    red[threadIdx.x] = (i < N_NODES) ? deg[i] : 0;
    __syncthreads();
    for (int off = 128; off > 0; off >>= 1) {
        if (threadIdx.x < off) red[threadIdx.x] += red[threadIdx.x + off];
        __syncthreads();
    }
    if (threadIdx.x == 0) partial[blockIdx.x] = red[0];
}

__global__ void scan2_kernel(const int* __restrict__ p0, const int* __restrict__ p1,
                             int* __restrict__ base0, int* __restrict__ base1,
                             int* __restrict__ rp0, int* __restrict__ rp1) {
    const int* partial = blockIdx.y ? p1 : p0;
    int* base          = blockIdx.y ? base1 : base0;
    int* row_ptr       = blockIdx.y ? rp1 : rp0;
    __shared__ int s[256];
    int t = threadIdx.x;
    int v = (t < NB_SCAN) ? partial[t] : 0;
    s[t] = v;
    __syncthreads();
    for (int off = 1; off < 256; off <<= 1) {
        int u = (t >= off) ? s[t - off] : 0;
        __syncthreads();
        s[t] += u;
        __syncthreads();
    }
    if (t < NB_SCAN) base[t] = s[t] - v;
    if (t == 255) row_ptr[N_NODES] = s[255];
}

__global__ void scan3_kernel(const int* __restrict__ deg0, const int* __restrict__ deg1,
                             const int* __restrict__ base0, const int* __restrict__ base1,
                             int* __restrict__ rp0, int* __restrict__ rp1,
                             int* __restrict__ cur0, int* __restrict__ cur1) {
    const int* deg  = blockIdx.y ? deg1 : deg0;
    const int* base = blockIdx.y ? base1 : base0;
    int* row_ptr    = blockIdx.y ? rp1 : rp0;
    int* cursor     = blockIdx.y ? cur1 : cur0;
    __shared__ int s[256];
    int i = blockIdx.x * 256 + threadIdx.x;
    int t = threadIdx.x;
    int v = (i < N_NODES) ? deg[i] : 0;
    s[t] = v;
    __syncthreads();
    for (int off = 1; off < 256; off <<= 1) {
        int u = (t >= off) ? s[t - off] : 0;
        __syncthreads();
        s[t] += u;
        __syncthreads();
    }
    if (i < N_NODES) {
        int ex = base[blockIdx.x] + s[t] - v;
        row_ptr[i] = ex;
        cursor[i]  = ex;
    }
}

// dst-partitioned fill: class c writes only dst in [c*NPC,(c+1)*NPC); ~50K cursors keep
// atomic contention ~32 hits/counter (R10 lesson: 782 counters = 659us disaster).
// Plain loads (R11 lesson: nt bypasses L3 -> 100MB HBM re-reads).
__global__ void fill_kernel(const int* __restrict__ ei0, const int* __restrict__ ei1,
                            int* __restrict__ cur0, int* __restrict__ cur1,
                            int2* __restrict__ csr0, int2* __restrict__ csr1) {
    const int* ei = blockIdx.y ? ei1 : ei0;
    int* cursor   = blockIdx.y ? cur1 : cur0;
    int2* csr     = blockIdx.y ? csr1 : csr0;
    int chunk = blockIdx.x >> 3;
    int cls   = blockIdx.x & 7;
    int e0 = chunk * FCHUNK;
    int e1 = e0 + FCHUNK; if (e1 > N_EDGES) e1 = N_EDGES;
    int lo = cls * NPC, hi = lo + NPC;
    for (int e = e0 + threadIdx.x; e < e1; e += 256) {
        int dst = ei[N_EDGES + e];
        if (dst >= lo && dst < hi) {
            int src = ei[e];
            int pos = atomicAdd(&cursor[dst], 1);
            csr[pos] = make_int2(src, e);
        }
    }
}

// ------------------------------------------------- edge-attr aggregation -> aggE[N][8] bf16
__global__ void gather_e_kernel(const float* __restrict__ ea0, const float* __restrict__ ea1,
                                const int* __restrict__ rp0, const int* __restrict__ rp1,
                                const int2* __restrict__ csr0, const int2* __restrict__ csr1,
                                unsigned short* __restrict__ aggE0,
                                unsigned short* __restrict__ aggE1) {
    const float* ea        = blockIdx.y ? ea1 : ea0;
    const int* row_ptr     = blockIdx.y ? rp1 : rp0;
    const int2* csr        = blockIdx.y ? csr1 : csr0;
    unsigned short* aggE   = blockIdx.y ? aggE1 : aggE0;
    int node = blockIdx.x * 32 + (threadIdx.x >> 3);
    if (node >= N_NODES) return;
    int lane = threadIdx.x & 7;
    int start = row_ptr[node], end = row_ptr[node + 1];
    float acc = 0.f;
    int e = start;
    for (; e + 2 <= end; e += 2) {
        int e0 = csr[e].y, e1 = csr[e + 1].y;
        acc += ea[(size_t)e0 * FE + lane] + ea[(size_t)e1 * FE + lane];
    }
    if (e < end) acc += ea[(size_t)csr[e].y * FE + lane];
    aggE[(size_t)node * FE + lane] = f2bf(acc);
}

// ---------------------------------------------------------------- fp32 -> bf16 (row-major)
__global__ void f2bf_kernel(const float* __restrict__ in0, const float* __restrict__ in1,
                            unsigned short* __restrict__ o0, unsigned short* __restrict__ o1) {
    const float* in       = blockIdx.y ? in1 : in0;
    unsigned short* out16 = blockIdx.y ? o1 : o0;
    int i = blockIdx.x * 256 + threadIdx.x;          // over N_NODES*FX/4
    if (i >= N_NODES * FX / 4) return;
    float4 v = reinterpret_cast<const float4*>(in)[i];
    ushort4 o;
    o.x = f2bf(v.x); o.y = f2bf(v.y); o.z = f2bf(v.z); o.w = f2bf(v.w);
    reinterpret_cast<ushort4*>(out16)[i] = o;
}

// --------------------------------------------- weight convert: fp32 -> bf16, K-pad to 160
__global__ void wcvt_kernel(const float* __restrict__ WA, const float* __restrict__ WB,
                            const float* __restrict__ fcW,
                            unsigned short* __restrict__ w16A, unsigned short* __restrict__ w16B,
                            unsigned short* __restrict__ w16fc) {
    const int CONV = 3 * FX * 160;                   // 61440 per branch
    int idx = blockIdx.x * 256 + threadIdx.x;
    if (idx < 2 * CONV) {
        int br = idx / CONV, r = idx % CONV;
        int l = r / (FX * 160), rem = r % (FX * 160);
        int row = rem / 160, k = rem % 160;
        const float* Wsrc = br ? WB : WA;
        float v = (k < FIN) ? Wsrc[((size_t)l * FX + row) * FIN + k] : 0.f;
        (br ? w16B : w16A)[r] = f2bf(v);
    } else {
        int i = idx - 2 * CONV;
        if (i < FX * FX) w16fc[i] = f2bf(fcW[i]);
    }
}

// ------------------------------------------- FUSED conv layer: gather -> LDS -> MFMA
// Phase 1 (R16): 16 groups x 16 lanes, uint4 8-deep per node (R12's known-best shape)
// but TWO nodes in flight per lane (vA[8]+vB[8] = 64 staging VGPRs) -> 16 outstanding
// misses/thread instead of 8, same load width/count. bounds(256,4): VGPR cap 128
// (R13/R14 lesson: caps 73/102 squeeze VGPR -> spill or lost ILP).
// Phase 2: 4-wave MFMA K=160, LeakyReLU. LAST=true: h3 -> LDS (aliased) -> fc MFMA -> fp32.
// Fragment maps (verified m89): A row=l&15, k=(l>>4)*8+j; B col=l&15, same k;
//                               C col=l&15, row=(l>>4)*4+reg.
template <bool LAST>
__global__ __launch_bounds__(256, 4)
void conv_fused_kernel(const unsigned short* __restrict__ hin0,
                       const unsigned short* __restrict__ hin1,
                       const int* __restrict__ rp0, const int* __restrict__ rp1,
                       const int2* __restrict__ csr0, const int2* __restrict__ csr1,
                       const unsigned short* __restrict__ aggE0,
                       const unsigned short* __restrict__ aggE1,
                       const unsigned short* __restrict__ W0,
                       const unsigned short* __restrict__ W1,
                       const float* __restrict__ b0, const float* __restrict__ b1,
                       unsigned short* __restrict__ hout0,
                       unsigned short* __restrict__ hout1,
                       const unsigned short* __restrict__ fcW16,
                       const float* __restrict__ fcb,
                       float* __restrict__ fout0, float* __restrict__ fout1) {
    const unsigned short* hin  = blockIdx.y ? hin1 : hin0;
    const int* row_ptr         = blockIdx.y ? rp1 : rp0;
    const int2* csr            = blockIdx.y ? csr1 : csr0;
    const unsigned short* aggE = blockIdx.y ? aggE1 : aggE0;
    const unsigned short* W16  = blockIdx.y ? W1 : W0;
    const float* bias          = blockIdx.y ? b1 : b0;

    __shared__ unsigned short As[64 * KP];           // 21504 B; Hs aliases into this
    const int row0 = blockIdx.x * 64;

    // ---- Phase 1: gather, two nodes in flight per 16-lane group
    {
        int grp  = threadIdx.x >> 4;
        int lane = threadIdx.x & 15;
        for (int pp = 0; pp < 4; pp += 2) {
            int rA = grp * 4 + pp, rB = rA + 1;
            int nodeA = row0 + rA, nodeB = row0 + rB;
            int eA = 0, eAend = 0, eB = 0, eBend = 0;
            if (nodeA < N_NODES) { eA = row_ptr[nodeA]; eAend = row_ptr[nodeA + 1]; }
            if (nodeB < N_NODES) { eB = row_ptr[nodeB]; eBend = row_ptr[nodeB + 1]; }
            float a[8] = {}, b[8] = {};
            // joint rounds: 16 outstanding loads
            while (eA + 8 <= eAend && eB + 8 <= eBend) {
                uint4 vA[8], vB[8];
#pragma unroll
                for (int k = 0; k < 8; ++k) {
                    int s = csr[eA + k].x;
                    vA[k] = *reinterpret_cast<const uint4*>(&hin[(size_t)s * FX + lane * 8]);
                }
#pragma unroll
                for (int k = 0; k < 8; ++k) {
                    int s = csr[eB + k].x;
                    vB[k] = *reinterpret_cast<const uint4*>(&hin[(size_t)s * FX + lane * 8]);
                }
#pragma unroll
                for (int k = 0; k < 8; ++k) {
#pragma unroll
                    for (int q = 0; q < 4; ++q) {
                        unsigned uA = (&vA[k].x)[q], uB = (&vB[k].x)[q];
                        a[q * 2]     += __uint_as_float(uA << 16);
                        a[q * 2 + 1] += __uint_as_float(uA & 0xffff0000u);
                        b[q * 2]     += __uint_as_float(uB << 16);
                        b[q * 2 + 1] += __uint_as_float(uB & 0xffff0000u);
                    }
                }
                eA += 8; eB += 8;
            }
            // drain A
            for (; eA + 8 <= eAend; eA += 8) {
                uint4 v[8];
#pragma unroll
                for (int k = 0; k < 8; ++k) {
                    int s = csr[eA + k].x;
                    v[k] = *reinterpret_cast<const uint4*>(&hin[(size_t)s * FX + lane * 8]);
                }
#pragma unroll
                for (int k = 0; k < 8; ++k)
#pragma unroll
                    for (int q = 0; q < 4; ++q) {
                        unsigned u = (&v[k].x)[q];
                        a[q * 2]     += __uint_as_float(u << 16);
                        a[q * 2 + 1] += __uint_as_float(u & 0xffff0000u);
                    }
            }
            for (; eA < eAend; ++eA) {
                uint4 v = *reinterpret_cast<const uint4*>(
                    &hin[(size_t)csr[eA].x * FX + lane * 8]);
#pragma unroll
                for (int q = 0; q < 4; ++q) {
                    unsigned u = (&v.x)[q];
                    a[q * 2]     += __uint_as_float(u << 16);
                    a[q * 2 + 1] += __uint_as_float(u & 0xffff0000u);
                }
            }
            // drain B
            for (; eB + 8 <= eBend; eB += 8) {
                uint4 v[8];
#pragma unroll
                for (int k = 0; k < 8; ++k) {
                    int s = csr[eB + k].x;
                    v[k] = *reinterpret_cast<const uint4*>(&hin[(size_t)s * FX + lane * 8]);
                }
#pragma unroll
                for (int k = 0; k < 8; ++k)
#pragma unroll
                    for (int q = 0; q < 4; ++q) {
                        unsigned u = (&v[k].x)[q];
                        b[q * 2]     += __uint_as_float(u << 16);
                        b[q * 2 + 1] += __uint_as_float(u & 0xffff0000u);
                    }
            }
            for (; eB < eBend; ++eB) {
                uint4 v = *reinterpret_cast<const uint4*>(
                    &hin[(size_t)csr[eB].x * FX + lane * 8]);
#pragma unroll
                for (int q = 0; q < 4; ++q) {
                    unsigned u = (&v.x)[q];
                    b[q * 2]     += __uint_as_float(u << 16);
                    b[q * 2 + 1] += __uint_as_float(u & 0xffff0000u);
                }
            }
            if (nodeA < N_NODES) {
                union { unsigned short us[8]; uint4 v; } o;
#pragma unroll
                for (int q = 0; q < 8; ++q) o.us[q] = f2bf(a[q]);
                *reinterpret_cast<uint4*>(&As[rA * KP + lane * 8]) = o.v;
            }
            if (nodeB < N_NODES) {
                union { unsigned short us[8]; uint4 v; } o;
#pragma unroll
                for (int q = 0; q < 8; ++q) o.us[q] = f2bf(b[q]);
                *reinterpret_cast<uint4*>(&As[rB * KP + lane * 8]) = o.v;
            }
        }
    }
    // ---- aggE cols 128..135 + zero pad 136..159 (64 rows x 4 16B-chunks)
    for (int idx = threadIdx.x; idx < 64 * 4; idx += 256) {
        int r = idx >> 2, c = idx & 3;
        uint4 v = {0u, 0u, 0u, 0u};
        if (c == 0) {
            int node = row0 + r;
            if (node < N_NODES)
                v = *reinterpret_cast<const uint4*>(&aggE[(size_t)node * FE]);
        }
        *reinterpret_cast<uint4*>(&As[r * KP + FX + c * 8]) = v;
    }
    __syncthreads();

    // ---- Phase 2: MFMA (K = 160, 5 steps)
    const int wid = threadIdx.x >> 6;
    const int l   = threadIdx.x & 63;
    const int l16 = l & 15, lhi = l >> 4;
    const unsigned short* Arow = &As[(wid * 16 + l16) * KP + lhi * 8];

    float4v acc[8];
#pragma unroll
    for (int f = 0; f < 8; ++f) acc[f] = (float4v){0.f, 0.f, 0.f, 0.f};

#pragma unroll
    for (int ks = 0; ks < 5; ++ks) {
        short8v a = *reinterpret_cast<const short8v*>(Arow + ks * 32);
#pragma unroll
        for (int f = 0; f < 8; ++f) {
            short8v b = *reinterpret_cast<const short8v*>(
                &W16[(size_t)(f * 16 + l16) * 160 + ks * 32 + lhi * 8]);
            acc[f] = __builtin_amdgcn_mfma_f32_16x16x32_bf16(a, b, acc[f], 0, 0, 0);
        }
    }

    float bs[8];
#pragma unroll
    for (int f = 0; f < 8; ++f) bs[f] = bias[f * 16 + l16];

    if constexpr (!LAST) {
        unsigned short* hout = blockIdx.y ? hout1 : hout0;
#pragma unroll
        for (int f = 0; f < 8; ++f) {
#pragma unroll
            for (int j = 0; j < 4; ++j) {
                int r = row0 + wid * 16 + lhi * 4 + j;
                if (r < N_NODES) {
                    float v = acc[f][j] + bs[f];
                    v = v > 0.f ? v : 0.01f * v;
                    hout[(size_t)r * FX + f * 16 + l16] = f2bf(v);
                }
            }
        }
    } else {
        // h3 (post-leaky) -> LDS aliased over As (all As reads done), then fc MFMA
        __syncthreads();                             // everyone finished reading As
        unsigned short* Hs = As;
#pragma unroll
        for (int f = 0; f < 8; ++f) {
#pragma unroll
            for (int j = 0; j < 4; ++j) {
                float v = acc[f][j] + bs[f];
                v = v > 0.f ? v : 0.01f * v;
                Hs[(wid * 16 + lhi * 4 + j) * KP2 + f * 16 + l16] = f2bf(v);
            }
        }
        __syncthreads();

        const unsigned short* Hrow = &Hs[(wid * 16 + l16) * KP2 + lhi * 8];
        float4v acc2[8];
#pragma unroll
        for (int f = 0; f < 8; ++f) acc2[f] = (float4v){0.f, 0.f, 0.f, 0.f};
#pragma unroll
        for (int ks = 0; ks < 4; ++ks) {
            short8v a = *reinterpret_cast<const short8v*>(Hrow + ks * 32);
#pragma unroll
            for (int f = 0; f < 8; ++f) {
                short8v b = *reinterpret_cast<const short8v*>(
                    &fcW16[(size_t)(f * 16 + l16) * FX + ks * 32 + lhi * 8]);
                acc2[f] = __builtin_amdgcn_mfma_f32_16x16x32_bf16(a, b, acc2[f], 0, 0, 0);
            }
        }
        float* fout = blockIdx.y ? fout1 : fout0;
        float bs2[8];
#pragma unroll
        for (int f = 0; f < 8; ++f) bs2[f] = fcb[f * 16 + l16];
#pragma unroll
        for (int f = 0; f < 8; ++f) {
#pragma unroll
            for (int j = 0; j < 4; ++j) {
                int r = row0 + wid * 16 + lhi * 4 + j;
                if (r < N_NODES)
                    fout[(size_t)r * FX + f * 16 + l16] = acc2[f][j] + bs2[f];
            }
        }
    }
}

// ---------------------------------------------------------------- launch
extern "C" void kernel_launch(void* const* d_in, const int* in_sizes, int n_in,
                              void* d_out, int out_size, void* d_ws, size_t ws_size,
                              hipStream_t stream) {
    const float* x1  = (const float*)d_in[0];
    const int*   ei1 = (const int*)  d_in[1];
    const float* ea1 = (const float*)d_in[2];
    const float* x2  = (const float*)d_in[3];
    const int*   ei2 = (const int*)  d_in[4];
    const float* ea2 = (const float*)d_in[5];
    const float* WA  = (const float*)d_in[6];
    const float* bA  = (const float*)d_in[7];
    const float* WB  = (const float*)d_in[8];
    const float* bB  = (const float*)d_in[9];
    const float* fcW = (const float*)d_in[10];
    const float* fcb = (const float*)d_in[11];
    float* out = (float*)d_out;

    // workspace layout
    unsigned short* hAa   = (unsigned short*)d_ws;           // NPAD*FX bf16 ping
    unsigned short* hAb   = hAa + (size_t)NPAD * FX;
    unsigned short* hBa   = hAb + (size_t)NPAD * FX;         // NPAD*FX bf16 pong
    unsigned short* hBb   = hBa + (size_t)NPAD * FX;
    unsigned short* aggEa = hBb + (size_t)NPAD * FX;         // NPAD*FE bf16
    unsigned short* aggEb = aggEa + (size_t)NPAD * FE;
    unsigned short* w16A  = aggEb + (size_t)NPAD * FE;       // 3*128*160
    unsigned short* w16B  = w16A + 3 * FX * 160;
    unsigned short* w16fc = w16B + 3 * FX * 160;             // 128*128
    int2* csr0 = (int2*)(((size_t)(w16fc + FX * FX) + 15) & ~(size_t)15);
    int2* csr1 = csr0 + N_EDGES;
    int* deg0  = (int*)(csr1 + N_EDGES);                     // deg0,deg1 contiguous
    int* deg1  = deg0 + N_NODES;
    int* rowp0 = deg1 + N_NODES;
    int* rowp1 = rowp0 + N_NODES + 1;
    int* cur0  = rowp1 + N_NODES + 1;
    int* cur1  = cur0 + N_NODES;
    int* part0 = cur1 + N_NODES;
    int* part1 = part0 + NB_SCAN;
    int* base0 = part1 + NB_SCAN;
    int* base1 = base0 + NB_SCAN;
    size_t needed = (size_t)(base1 + NB_SCAN) - (size_t)d_ws;
    if (ws_size < needed) return;                            // output stays poisoned

    const dim3 b256(256);
    const dim3 gE(6250, 2);                       // edges / 256
    const dim3 gS(NB_SCAN, 2);
    const dim3 g1(1, 2);
    const dim3 gF(NCHUNK * NXCD, 2);              // 6256
    const dim3 gGE(1563, 2);
    const dim3 gC(6250, 2);
    const dim3 gM(782, 2);
    const dim3 gW(544);

    // CSR build, both branches fused per dispatch
    (void)hipMemsetAsync(deg0, 0, 2 * N_NODES * sizeof(int), stream);
    hist_kernel<<<gE, b256, 0, stream>>>(ei1, ei2, deg0, deg1);
    scan1_kernel<<<gS, b256, 0, stream>>>(deg0, deg1, part0, part1);
    scan2_kernel<<<g1, b256, 0, stream>>>(part0, part1, base0, base1, rowp0, rowp1);
    scan3_kernel<<<gS, b256, 0, stream>>>(deg0, deg1, base0, base1, rowp0, rowp1, cur0, cur1);
    fill_kernel<<<gF, b256, 0, stream>>>(ei1, ei2, cur0, cur1, csr0, csr1);

    // layer-invariant pieces
    gather_e_kernel<<<gGE, b256, 0, stream>>>(ea1, ea2, rowp0, rowp1, csr0, csr1, aggEa, aggEb);
    f2bf_kernel<<<gC, b256, 0, stream>>>(x1, x2, hAa, hAb);
    wcvt_kernel<<<gW, b256, 0, stream>>>(WA, WB, fcW, w16A, w16B, w16fc);

    // conv layers 1-2 (gather -> LDS -> MFMA), ping-pong; layer 3 fuses fc -> fp32 out
    conv_fused_kernel<false><<<gM, b256, 0, stream>>>(
        hAa, hAb, rowp0, rowp1, csr0, csr1, aggEa, aggEb,
        w16A, w16B, bA, bB, hBa, hBb, nullptr, nullptr, nullptr, nullptr);
    conv_fused_kernel<false><<<gM, b256, 0, stream>>>(
        hBa, hBb, rowp0, rowp1, csr0, csr1, aggEa, aggEb,
        w16A + (size_t)FX * 160, w16B + (size_t)FX * 160,
        bA + FX, bB + FX, hAa, hAb, nullptr, nullptr, nullptr, nullptr);
    conv_fused_kernel<true><<<gM, b256, 0, stream>>>(
        hAa, hAb, rowp0, rowp1, csr0, csr1, aggEa, aggEb,
        w16A + (size_t)2 * FX * 160, w16B + (size_t)2 * FX * 160,
        bA + 2 * FX, bB + 2 * FX, nullptr, nullptr,
        w16fc, fcb, out, out + (size_t)N_NODES * FX);
}

// Round 17
// 784.667 us; speedup vs baseline: 1.1892x; 1.1892x over previous
//
#include <hip/hip_runtime.h>

#define N_NODES 50000
#define N_EDGES 1600000
#define FX 128
#define FE 8
#define FIN 136          // FX + FE
#define NPAD 50048       // pad rows so 64-row tiles can over-read safely
#define NB_SCAN 196      // ceil(N_NODES / 256)
#define NXCD 8
#define NPC 6250         // nodes per dst class (fill partitioning)
#define FCHUNK 2048      // edges per chunk in fill
#define NCHUNK ((N_EDGES + FCHUNK - 1) / FCHUNK)   // 782
#define KP 168           // LDS A stride (elems)
#define KP2 136          // LDS h3 stride for fused fc (elems)

typedef short short8v __attribute__((ext_vector_type(8)));
typedef float float4v __attribute__((ext_vector_type(4)));

__device__ inline float bf2f(unsigned short h) {
    return __uint_as_float((unsigned)h << 16);
}
__device__ inline unsigned short f2bf(float f) {   // round-to-nearest-even
    unsigned u = __float_as_uint(f);
    u = (u + 0x7FFF + ((u >> 16) & 1)) >> 16;
    return (unsigned short)u;
}

// ---------------------------------------------------------------- CSR build (y = branch)
__global__ void hist_kernel(const int* __restrict__ ei0, const int* __restrict__ ei1,
                            int* __restrict__ deg0, int* __restrict__ deg1) {
    const int* ei = blockIdx.y ? ei1 : ei0;
    int* deg      = blockIdx.y ? deg1 : deg0;
    int e = blockIdx.x * 256 + threadIdx.x;
    if (e >= N_EDGES) return;
    atomicAdd(&deg[ei[N_EDGES + e]], 1);             // plain load: leave dst L3-resident
}

__global__ void scan1_kernel(const int* __restrict__ deg0, const int* __restrict__ deg1,
                             int* __restrict__ p0, int* __restrict__ p1) {
    const int* deg = blockIdx.y ? deg1 : deg0;
    int* partial   = blockIdx.y ? p1 : p0;
    __shared__ int red[256];
    int i = blockIdx.x * 256 + threadIdx.x;
    red[threadIdx.x] = (i < N_NODES) ? deg[i] : 0;
    __syncthreads();
    for (int off = 128; off > 0; off >>= 1) {
        if (threadIdx.x < off) red[threadIdx.x] += red[threadIdx.x + off];
        __syncthreads();
    }
    if (threadIdx.x == 0) partial[blockIdx.x] = red[0];
}

__global__ void scan2_kernel(const int* __restrict__ p0, const int* __restrict__ p1,
                             int* __restrict__ base0, int* __restrict__ base1,
                             int* __restrict__ rp0, int* __restrict__ rp1) {
    const int* partial = blockIdx.y ? p1 : p0;
    int* base          = blockIdx.y ? base1 : base0;
    int* row_ptr       = blockIdx.y ? rp1 : rp0;
    __shared__ int s[256];
    int t = threadIdx.x;
    int v = (t < NB_SCAN) ? partial[t] : 0;
    s[t] = v;
    __syncthreads();
    for (int off = 1; off < 256; off <<= 1) {
        int u = (t >= off) ? s[t - off] : 0;
        __syncthreads();
        s[t] += u;
        __syncthreads();
    }
    if (t < NB_SCAN) base[t] = s[t] - v;
    if (t == 255) row_ptr[N_NODES] = s[255];
}

__global__ void scan3_kernel(const int* __restrict__ deg0, const int* __restrict__ deg1,
                             const int* __restrict__ base0, const int* __restrict__ base1,
                             int* __restrict__ rp0, int* __restrict__ rp1,
                             int* __restrict__ cur0, int* __restrict__ cur1) {
    const int* deg  = blockIdx.y ? deg1 : deg0;
    const int* base = blockIdx.y ? base1 : base0;
    int* row_ptr    = blockIdx.y ? rp1 : rp0;
    int* cursor     = blockIdx.y ? cur1 : cur0;
    __shared__ int s[256];
    int i = blockIdx.x * 256 + threadIdx.x;
    int t = threadIdx.x;
    int v = (i < N_NODES) ? deg[i] : 0;
    s[t] = v;
    __syncthreads();
    for (int off = 1; off < 256; off <<= 1) {
        int u = (t >= off) ? s[t - off] : 0;
        __syncthreads();
        s[t] += u;
        __syncthreads();
    }
    if (i < N_NODES) {
        int ex = base[blockIdx.x] + s[t] - v;
        row_ptr[i] = ex;
        cursor[i]  = ex;
    }
}

// dst-partitioned fill: class c writes only dst in [c*NPC,(c+1)*NPC); ~50K cursors keep
// atomic contention ~32 hits/counter (R10 lesson: 782 counters = 659us disaster).
// Plain loads (R11 lesson: nt bypasses L3 -> 100MB HBM re-reads).
__global__ void fill_kernel(const int* __restrict__ ei0, const int* __restrict__ ei1,
                            int* __restrict__ cur0, int* __restrict__ cur1,
                            int2* __restrict__ csr0, int2* __restrict__ csr1) {
    const int* ei = blockIdx.y ? ei1 : ei0;
    int* cursor   = blockIdx.y ? cur1 : cur0;
    int2* csr     = blockIdx.y ? csr1 : csr0;
    int chunk = blockIdx.x >> 3;
    int cls   = blockIdx.x & 7;
    int e0 = chunk * FCHUNK;
    int e1 = e0 + FCHUNK; if (e1 > N_EDGES) e1 = N_EDGES;
    int lo = cls * NPC, hi = lo + NPC;
    for (int e = e0 + threadIdx.x; e < e1; e += 256) {
        int dst = ei[N_EDGES + e];
        if (dst >= lo && dst < hi) {
            int src = ei[e];
            int pos = atomicAdd(&cursor[dst], 1);
            csr[pos] = make_int2(src, e);
        }
    }
}

// ------------------------------------------------- edge-attr aggregation -> aggE[N][8] bf16
__global__ void gather_e_kernel(const float* __restrict__ ea0, const float* __restrict__ ea1,
                                const int* __restrict__ rp0, const int* __restrict__ rp1,
                                const int2* __restrict__ csr0, const int2* __restrict__ csr1,
                                unsigned short* __restrict__ aggE0,
                                unsigned short* __restrict__ aggE1) {
    const float* ea        = blockIdx.y ? ea1 : ea0;
    const int* row_ptr     = blockIdx.y ? rp1 : rp0;
    const int2* csr        = blockIdx.y ? csr1 : csr0;
    unsigned short* aggE   = blockIdx.y ? aggE1 : aggE0;
    int node = blockIdx.x * 32 + (threadIdx.x >> 3);
    if (node >= N_NODES) return;
    int lane = threadIdx.x & 7;
    int start = row_ptr[node], end = row_ptr[node + 1];
    float acc = 0.f;
    int e = start;
    for (; e + 2 <= end; e += 2) {
        int e0 = csr[e].y, e1 = csr[e + 1].y;
        acc += ea[(size_t)e0 * FE + lane] + ea[(size_t)e1 * FE + lane];
    }
    if (e < end) acc += ea[(size_t)csr[e].y * FE + lane];
    aggE[(size_t)node * FE + lane] = f2bf(acc);
}

// ---------------------------------------------------------------- fp32 -> bf16 (row-major)
__global__ void f2bf_kernel(const float* __restrict__ in0, const float* __restrict__ in1,
                            unsigned short* __restrict__ o0, unsigned short* __restrict__ o1) {
    const float* in       = blockIdx.y ? in1 : in0;
    unsigned short* out16 = blockIdx.y ? o1 : o0;
    int i = blockIdx.x * 256 + threadIdx.x;          // over N_NODES*FX/4
    if (i >= N_NODES * FX / 4) return;
    float4 v = reinterpret_cast<const float4*>(in)[i];
    ushort4 o;
    o.x = f2bf(v.x); o.y = f2bf(v.y); o.z = f2bf(v.z); o.w = f2bf(v.w);
    reinterpret_cast<ushort4*>(out16)[i] = o;
}

// --------------------------------------------- weight convert: fp32 -> bf16, K-pad to 160
__global__ void wcvt_kernel(const float* __restrict__ WA, const float* __restrict__ WB,
                            const float* __restrict__ fcW,
                            unsigned short* __restrict__ w16A, unsigned short* __restrict__ w16B,
                            unsigned short* __restrict__ w16fc) {
    const int CONV = 3 * FX * 160;                   // 61440 per branch
    int idx = blockIdx.x * 256 + threadIdx.x;
    if (idx < 2 * CONV) {
        int br = idx / CONV, r = idx % CONV;
        int l = r / (FX * 160), rem = r % (FX * 160);
        int row = rem / 160, k = rem % 160;
        const float* Wsrc = br ? WB : WA;
        float v = (k < FIN) ? Wsrc[((size_t)l * FX + row) * FIN + k] : 0.f;
        (br ? w16B : w16A)[r] = f2bf(v);
    } else {
        int i = idx - 2 * CONV;
        if (i < FX * FX) w16fc[i] = f2bf(fcW[i]);
    }
}

// ------------------------------------------- FUSED conv layer: gather -> LDS -> MFMA
// R12-measured optimum (785us total, conv 153us, VGPR 60, no spill). Perturbations all
// regressed: bounds 7 (spill, R13), bounds 5 (VGPR squeeze, R14), uint2x16 (2x load
// count, R15), dual-node uint4 (spill, R16). Gather demand ~819MB/dispatch @ ~5.3TB/s
// effective = ~85% of streaming ceiling for a RANDOM pattern -> at service roofline.
// Phase 1: 16 groups x 16 lanes gather x[src] rows into LDS (uint4, 8-deep);
// aggE -> cols 128..135; 136..159 zeroed. Phase 2: 4-wave MFMA K=160, LeakyReLU.
// LAST=true: h3 -> Hs LDS -> second MFMA with fcW (K=128) -> fp32 out.
// Fragment maps (verified m89): A row=l&15, k=(l>>4)*8+j; B col=l&15, same k;
//                               C col=l&15, row=(l>>4)*4+reg.
template <bool LAST>
__global__ __launch_bounds__(256, 4)
void conv_fused_kernel(const unsigned short* __restrict__ hin0,
                       const unsigned short* __restrict__ hin1,
                       const int* __restrict__ rp0, const int* __restrict__ rp1,
                       const int2* __restrict__ csr0, const int2* __restrict__ csr1,
                       const unsigned short* __restrict__ aggE0,
                       const unsigned short* __restrict__ aggE1,
                       const unsigned short* __restrict__ W0,
                       const unsigned short* __restrict__ W1,
                       const float* __restrict__ b0, const float* __restrict__ b1,
                       unsigned short* __restrict__ hout0,
                       unsigned short* __restrict__ hout1,
                       const unsigned short* __restrict__ fcW16,
                       const float* __restrict__ fcb,
                       float* __restrict__ fout0, float* __restrict__ fout1) {
    const unsigned short* hin  = blockIdx.y ? hin1 : hin0;
    const int* row_ptr         = blockIdx.y ? rp1 : rp0;
    const int2* csr            = blockIdx.y ? csr1 : csr0;
    const unsigned short* aggE = blockIdx.y ? aggE1 : aggE0;
    const unsigned short* W16  = blockIdx.y ? W1 : W0;
    const float* bias          = blockIdx.y ? b1 : b0;

    __shared__ unsigned short As[64 * KP];
    __shared__ unsigned short Hs[LAST ? 64 * KP2 : 1];
    const int row0 = blockIdx.x * 64;

    // ---- Phase 1: gather 4 nodes per 16-lane group
    {
        int grp  = threadIdx.x >> 4;
        int lane = threadIdx.x & 15;
        for (int nn = 0; nn < 4; ++nn) {
            int r = grp * 4 + nn;
            int node = row0 + r;
            if (node < N_NODES) {
                int start = row_ptr[node], end = row_ptr[node + 1];
                float a[8] = {};
                int e = start;
                for (; e + 8 <= end; e += 8) {
                    uint4 v[8];
#pragma unroll
                    for (int k = 0; k < 8; ++k) {
                        int s = csr[e + k].x;
                        v[k] = *reinterpret_cast<const uint4*>(&hin[(size_t)s * FX + lane * 8]);
                    }
#pragma unroll
                    for (int k = 0; k < 8; ++k) {
#pragma unroll
                        for (int q = 0; q < 4; ++q) {
                            unsigned u = (&v[k].x)[q];
                            a[q * 2]     += __uint_as_float(u << 16);
                            a[q * 2 + 1] += __uint_as_float(u & 0xffff0000u);
                        }
                    }
                }
                for (; e < end; ++e) {
                    uint4 v = *reinterpret_cast<const uint4*>(
                        &hin[(size_t)csr[e].x * FX + lane * 8]);
#pragma unroll
                    for (int q = 0; q < 4; ++q) {
                        unsigned u = (&v.x)[q];
                        a[q * 2]     += __uint_as_float(u << 16);
                        a[q * 2 + 1] += __uint_as_float(u & 0xffff0000u);
                    }
                }
                union { unsigned short us[8]; uint4 v; } o;
#pragma unroll
                for (int q = 0; q < 8; ++q) o.us[q] = f2bf(a[q]);
                *reinterpret_cast<uint4*>(&As[r * KP + lane * 8]) = o.v;
            }
        }
    }
    // ---- aggE cols 128..135 + zero pad 136..159 (64 rows x 4 16B-chunks)
    for (int idx = threadIdx.x; idx < 64 * 4; idx += 256) {
        int r = idx >> 2, c = idx & 3;
        uint4 v = {0u, 0u, 0u, 0u};
        if (c == 0) {
            int node = row0 + r;
            if (node < N_NODES)
                v = *reinterpret_cast<const uint4*>(&aggE[(size_t)node * FE]);
        }
        *reinterpret_cast<uint4*>(&As[r * KP + FX + c * 8]) = v;
    }
    __syncthreads();

    // ---- Phase 2: MFMA (K = 160, 5 steps)
    const int wid = threadIdx.x >> 6;
    const int l   = threadIdx.x & 63;
    const int l16 = l & 15, lhi = l >> 4;
    const unsigned short* Arow = &As[(wid * 16 + l16) * KP + lhi * 8];

    float4v acc[8];
#pragma unroll
    for (int f = 0; f < 8; ++f) acc[f] = (float4v){0.f, 0.f, 0.f, 0.f};

#pragma unroll
    for (int ks = 0; ks < 5; ++ks) {
        short8v a = *reinterpret_cast<const short8v*>(Arow + ks * 32);
#pragma unroll
        for (int f = 0; f < 8; ++f) {
            short8v b = *reinterpret_cast<const short8v*>(
                &W16[(size_t)(f * 16 + l16) * 160 + ks * 32 + lhi * 8]);
            acc[f] = __builtin_amdgcn_mfma_f32_16x16x32_bf16(a, b, acc[f], 0, 0, 0);
        }
    }

    float bs[8];
#pragma unroll
    for (int f = 0; f < 8; ++f) bs[f] = bias[f * 16 + l16];

    if constexpr (!LAST) {
        unsigned short* hout = blockIdx.y ? hout1 : hout0;
#pragma unroll
        for (int f = 0; f < 8; ++f) {
#pragma unroll
            for (int j = 0; j < 4; ++j) {
                int r = row0 + wid * 16 + lhi * 4 + j;
                if (r < N_NODES) {
                    float v = acc[f][j] + bs[f];
                    v = v > 0.f ? v : 0.01f * v;
                    hout[(size_t)r * FX + f * 16 + l16] = f2bf(v);
                }
            }
        }
    } else {
        // h3 (post-leaky) -> LDS, then fc MFMA (K=128) -> fp32 out
#pragma unroll
        for (int f = 0; f < 8; ++f) {
#pragma unroll
            for (int j = 0; j < 4; ++j) {
                float v = acc[f][j] + bs[f];
                v = v > 0.f ? v : 0.01f * v;
                Hs[(wid * 16 + lhi * 4 + j) * KP2 + f * 16 + l16] = f2bf(v);
            }
        }
        __syncthreads();

        const unsigned short* Hrow = &Hs[(wid * 16 + l16) * KP2 + lhi * 8];
        float4v acc2[8];
#pragma unroll
        for (int f = 0; f < 8; ++f) acc2[f] = (float4v){0.f, 0.f, 0.f, 0.f};
#pragma unroll
        for (int ks = 0; ks < 4; ++ks) {
            short8v a = *reinterpret_cast<const short8v*>(Hrow + ks * 32);
#pragma unroll
            for (int f = 0; f < 8; ++f) {
                short8v b = *reinterpret_cast<const short8v*>(
                    &fcW16[(size_t)(f * 16 + l16) * FX + ks * 32 + lhi * 8]);
                acc2[f] = __builtin_amdgcn_mfma_f32_16x16x32_bf16(a, b, acc2[f], 0, 0, 0);
            }
        }
        float* fout = blockIdx.y ? fout1 : fout0;
        float bs2[8];
#pragma unroll
        for (int f = 0; f < 8; ++f) bs2[f] = fcb[f * 16 + l16];
#pragma unroll
        for (int f = 0; f < 8; ++f) {
#pragma unroll
            for (int j = 0; j < 4; ++j) {
                int r = row0 + wid * 16 + lhi * 4 + j;
                if (r < N_NODES)
                    fout[(size_t)r * FX + f * 16 + l16] = acc2[f][j] + bs2[f];
            }
        }
    }
}

// ---------------------------------------------------------------- launch
extern "C" void kernel_launch(void* const* d_in, const int* in_sizes, int n_in,
                              void* d_out, int out_size, void* d_ws, size_t ws_size,
                              hipStream_t stream) {
    const float* x1  = (const float*)d_in[0];
    const int*   ei1 = (const int*)  d_in[1];
    const float* ea1 = (const float*)d_in[2];
    const float* x2  = (const float*)d_in[3];
    const int*   ei2 = (const int*)  d_in[4];
    const float* ea2 = (const float*)d_in[5];
    const float* WA  = (const float*)d_in[6];
    const float* bA  = (const float*)d_in[7];
    const float* WB  = (const float*)d_in[8];
    const float* bB  = (const float*)d_in[9];
    const float* fcW = (const float*)d_in[10];
    const float* fcb = (const float*)d_in[11];
    float* out = (float*)d_out;

    // workspace layout
    unsigned short* hAa   = (unsigned short*)d_ws;           // NPAD*FX bf16 ping
    unsigned short* hAb   = hAa + (size_t)NPAD * FX;
    unsigned short* hBa   = hAb + (size_t)NPAD * FX;         // NPAD*FX bf16 pong
    unsigned short* hBb   = hBa + (size_t)NPAD * FX;
    unsigned short* aggEa = hBb + (size_t)NPAD * FX;         // NPAD*FE bf16
    unsigned short* aggEb = aggEa + (size_t)NPAD * FE;
    unsigned short* w16A  = aggEb + (size_t)NPAD * FE;       // 3*128*160
    unsigned short* w16B  = w16A + 3 * FX * 160;
    unsigned short* w16fc = w16B + 3 * FX * 160;             // 128*128
    int2* csr0 = (int2*)(((size_t)(w16fc + FX * FX) + 15) & ~(size_t)15);
    int2* csr1 = csr0 + N_EDGES;
    int* deg0  = (int*)(csr1 + N_EDGES);                     // deg0,deg1 contiguous
    int* deg1  = deg0 + N_NODES;
    int* rowp0 = deg1 + N_NODES;
    int* rowp1 = rowp0 + N_NODES + 1;
    int* cur0  = rowp1 + N_NODES + 1;
    int* cur1  = cur0 + N_NODES;
    int* part0 = cur1 + N_NODES;
    int* part1 = part0 + NB_SCAN;
    int* base0 = part1 + NB_SCAN;
    int* base1 = base0 + NB_SCAN;
    size_t needed = (size_t)(base1 + NB_SCAN) - (size_t)d_ws;
    if (ws_size < needed) return;                            // output stays poisoned

    const dim3 b256(256);
    const dim3 gE(6250, 2);                       // edges / 256
    const dim3 gS(NB_SCAN, 2);
    const dim3 g1(1, 2);
    const dim3 gF(NCHUNK * NXCD, 2);              // 6256
    const dim3 gGE(1563, 2);
    const dim3 gC(6250, 2);
    const dim3 gM(782, 2);
    const dim3 gW(544);

    // CSR build, both branches fused per dispatch
    (void)hipMemsetAsync(deg0, 0, 2 * N_NODES * sizeof(int), stream);
    hist_kernel<<<gE, b256, 0, stream>>>(ei1, ei2, deg0, deg1);
    scan1_kernel<<<gS, b256, 0, stream>>>(deg0, deg1, part0, part1);
    scan2_kernel<<<g1, b256, 0, stream>>>(part0, part1, base0, base1, rowp0, rowp1);
    scan3_kernel<<<gS, b256, 0, stream>>>(deg0, deg1, base0, base1, rowp0, rowp1, cur0, cur1);
    fill_kernel<<<gF, b256, 0, stream>>>(ei1, ei2, cur0, cur1, csr0, csr1);

    // layer-invariant pieces
    gather_e_kernel<<<gGE, b256, 0, stream>>>(ea1, ea2, rowp0, rowp1, csr0, csr1, aggEa, aggEb);
    f2bf_kernel<<<gC, b256, 0, stream>>>(x1, x2, hAa, hAb);
    wcvt_kernel<<<gW, b256, 0, stream>>>(WA, WB, fcW, w16A, w16B, w16fc);

    // conv layers 1-2 (gather -> LDS -> MFMA), ping-pong; layer 3 fuses fc -> fp32 out
    conv_fused_kernel<false><<<gM, b256, 0, stream>>>(
        hAa, hAb, rowp0, rowp1, csr0, csr1, aggEa, aggEb,
        w16A, w16B, bA, bB, hBa, hBb, nullptr, nullptr, nullptr, nullptr);
    conv_fused_kernel<false><<<gM, b256, 0, stream>>>(
        hBa, hBb, rowp0, rowp1, csr0, csr1, aggEa, aggEb,
        w16A + (size_t)FX * 160, w16B + (size_t)FX * 160,
        bA + FX, bB + FX, hAa, hAb, nullptr, nullptr, nullptr, nullptr);
    conv_fused_kernel<true><<<gM, b256, 0, stream>>>(
        hAa, hAb, rowp0, rowp1, csr0, csr1, aggEa, aggEb,
        w16A + (size_t)2 * FX * 160, w16B + (size_t)2 * FX * 160,
        bA + 2 * FX, bB + 2 * FX, nullptr, nullptr,
        w16fc, fcb, out, out + (size_t)N_NODES * FX);
}